// Round 4
// baseline (77.238 us; speedup 1.0000x reference)
//
#include <hip/hip_runtime.h>
#include <math.h>

#define B_    4
#define TDEC  512
#define TENC  1024
#define H_    128
#define DT    4
#define NG    (H_ / 4)

__device__ float g_tet[B_ * H_ * TENC];                 // tanh(enc) transposed [b][h][e]
__device__ float g_tdt[B_ * TDEC * H_];                 // tanh(W dec + b)      [row][k]
__device__ float g_scr[(size_t)B_ * TDEC * TENC];       // raw scores           [row][e]

union F4 { float4 v; float f[4]; };

__device__ __forceinline__ float ftanh(float x) {
    // tanh(x) = 1 - 2/(e^{2x}+1)
    float e = __expf(2.f * x);
    return fmaf(-2.f, __builtin_amdgcn_rcpf(e + 1.f), 1.f);
}

// z<4: tet[b][h][e] = tanh(enc[b][e][h]) (tiled transpose).  z==4: TD rows.
__global__ __launch_bounds__(256) void prep_kernel(const float* __restrict__ enc,
                                                   const float* __restrict__ dec,
                                                   const float* __restrict__ Ww,
                                                   const float* __restrict__ Wb) {
    const int z = blockIdx.z;
    if (z < B_) {
        __shared__ float tile[32][33];
        const int e0 = blockIdx.x * 32, h0 = blockIdx.y * 32, b = z;
        const int tx = threadIdx.x, ty = threadIdx.y;
        const float* ep = enc + (size_t)b * TENC * H_;
        #pragma unroll
        for (int j = 0; j < 32; j += 8)
            tile[ty + j][tx] = ep[(size_t)(e0 + ty + j) * H_ + h0 + tx];
        __syncthreads();
        float* tp = g_tet + (size_t)b * H_ * TENC;
        #pragma unroll
        for (int j = 0; j < 32; j += 8)
            tp[(size_t)(h0 + ty + j) * TENC + e0 + tx] = ftanh(tile[tx][ty + j]);
    } else {
        // TD: 128 blocks, each computes 16 rows of tanh(dec @ Ww^T + Wb)
        __shared__ float ds[16][H_];
        const int t = threadIdx.y * 32 + threadIdx.x;
        const int blk = blockIdx.y * 32 + blockIdx.x;        // 0..127
        const int R0 = blk * 16;
        #pragma unroll
        for (int i = 0; i < 8; ++i) {
            const int f = t + 256 * i;
            ds[f >> 7][f & 127] = dec[(size_t)R0 * H_ + f];
        }
        __syncthreads();
        const int k = t & 127, dd = t >> 7;
        const float* wr = Ww + (size_t)k * H_;
        float s[8];
        #pragma unroll
        for (int j = 0; j < 8; ++j) s[j] = 0.f;
        for (int h = 0; h < H_; h += 4) {
            const float4 w4 = *(const float4*)(wr + h);
            #pragma unroll
            for (int j = 0; j < 8; ++j) {
                const float4 d4 = *(const float4*)&ds[dd + 2 * j][h];
                s[j] = fmaf(w4.x, d4.x, s[j]);
                s[j] = fmaf(w4.y, d4.y, s[j]);
                s[j] = fmaf(w4.z, d4.z, s[j]);
                s[j] = fmaf(w4.w, d4.w, s[j]);
            }
        }
        const float wb = Wb[k];
        #pragma unroll
        for (int j = 0; j < 8; ++j)
            g_tdt[(size_t)(R0 + dd + 2 * j) * H_ + k] = ftanh(s[j] + wb);
    }
}

// scores: block = (b, d-tile of 4, e-half of 512); thread owns 1 e, 4 d accs.
// Barrier-free inner loop; td/V/V*td broadcast from LDS; te streamed from L2.
__global__ __launch_bounds__(512, 8) void score_kernel(const float* __restrict__ Vw) {
    __shared__ float Vs[H_];
    __shared__ float TDs[DT][H_];
    __shared__ float VTs[DT][H_];
    const int t = threadIdx.x;
    const int blk = blockIdx.x;
    const int eh = blk & 1, dt = (blk >> 1) & 127, b = blk >> 8;
    const int R0 = b * TDEC + dt * DT;

    {
        const int row = t >> 7, k = t & 127;
        const float td = g_tdt[(size_t)(R0 + row) * H_ + k];
        TDs[row][k] = td;
        VTs[row][k] = Vw[k] * td;
        if (t < H_) Vs[t] = Vw[t];
    }
    __syncthreads();

    const float* teb = g_tet + (size_t)b * H_ * TENC + eh * 512 + t;
    F4 acc; acc.v = make_float4(0.f, 0.f, 0.f, 0.f);

    for (int g = 0; g < NG; ++g) {
        const float te0 = teb[(size_t)(4 * g + 0) * TENC];
        const float te1 = teb[(size_t)(4 * g + 1) * TENC];
        const float te2 = teb[(size_t)(4 * g + 2) * TENC];
        const float te3 = teb[(size_t)(4 * g + 3) * TENC];
        F4 v4; v4.v = *(const float4*)&Vs[4 * g];
        #pragma unroll
        for (int d = 0; d < DT; ++d) {
            F4 td4, vt4;
            td4.v = *(const float4*)&TDs[d][4 * g];
            vt4.v = *(const float4*)&VTs[d][4 * g];
            const float p0 = fmaf(td4.f[0], te0, 1.f);
            const float p1 = fmaf(td4.f[1], te1, 1.f);
            const float p2 = fmaf(td4.f[2], te2, 1.f);
            const float p3 = fmaf(td4.f[3], te3, 1.f);
            const float x0 = fmaf(v4.f[0], te0, vt4.f[0]);
            const float x1 = fmaf(v4.f[1], te1, vt4.f[1]);
            const float x2 = fmaf(v4.f[2], te2, vt4.f[2]);
            const float x3 = fmaf(v4.f[3], te3, vt4.f[3]);
            const float p01 = p0 * p1, p23 = p2 * p3;
            const float u = fmaf(x1, p0, x0 * p1);
            const float z = fmaf(x3, p2, x2 * p3);
            const float num = fmaf(z, p01, u * p23);
            acc.f[d] = fmaf(num, __builtin_amdgcn_rcpf(p01 * p23), acc.f[d]);
        }
    }
    float* so = g_scr + (size_t)R0 * TENC + eh * 512 + t;
    #pragma unroll
    for (int d = 0; d < DT; ++d) so[(size_t)d * TENC] = acc.f[d];
}

// softmax + context: block = (b, d-tile of 4, h-half of 64)
__global__ __launch_bounds__(512, 8) void smctx_kernel(const float* __restrict__ enc,
                                                       float* __restrict__ out) {
    __shared__ float sc[DT][TENC];
    __shared__ float2 part[16][DT][33];
    __shared__ float maxp[2][DT], sump[2][DT];
    const int t = threadIdx.x;
    const int blk = blockIdx.x;
    const int hh = blk & 1, dt = (blk >> 1) & 127, b = blk >> 8;
    const int R0 = b * TDEC + dt * DT;

    // softmax: wave w -> (d = w&3, e-half = w>>2), 8 e per lane
    {
        const int w = t >> 6, lane = t & 63;
        const int d = w & 3, eh = w >> 2;
        const float* sr = g_scr + (size_t)(R0 + d) * TENC + eh * 512 + lane;
        float v[8];
        float m = -3.0e38f;
        #pragma unroll
        for (int i = 0; i < 8; ++i) { v[i] = sr[i * 64]; m = fmaxf(m, v[i]); }
        #pragma unroll
        for (int off = 32; off; off >>= 1) m = fmaxf(m, __shfl_xor(m, off));
        if (lane == 0) maxp[eh][d] = m;
        __syncthreads();
        m = fmaxf(maxp[0][d], maxp[1][d]);
        float s = 0.f;
        #pragma unroll
        for (int i = 0; i < 8; ++i) {
            const float p = __expf(v[i] - m);
            sc[d][eh * 512 + lane + i * 64] = p;
            s += p;
        }
        #pragma unroll
        for (int off = 32; off; off >>= 1) s += __shfl_xor(s, off);
        if (lane == 0) sump[eh][d] = s;
    }
    __syncthreads();

    // context for this h-half: thread = (q = e-slice of 64, h2 = float2 col)
    {
        const int q = t >> 5, h2 = t & 31;
        const float* eb = enc + (size_t)b * TENC * H_ + hh * 64 + 2 * h2;
        float2 acc[DT];
        #pragma unroll
        for (int d = 0; d < DT; ++d) acc[d] = make_float2(0.f, 0.f);
        for (int e = q * 64; e < q * 64 + 64; e += 4) {
            F4 p4[DT];
            #pragma unroll
            for (int d = 0; d < DT; ++d) p4[d].v = *(const float4*)&sc[d][e];
            #pragma unroll
            for (int j = 0; j < 4; ++j) {
                const float2 ev = *(const float2*)(eb + (size_t)(e + j) * H_);
                #pragma unroll
                for (int d = 0; d < DT; ++d) {
                    acc[d].x = fmaf(p4[d].f[j], ev.x, acc[d].x);
                    acc[d].y = fmaf(p4[d].f[j], ev.y, acc[d].y);
                }
            }
        }
        #pragma unroll
        for (int d = 0; d < DT; ++d) part[q][d][h2] = acc[d];
    }
    __syncthreads();

    if (t < 128) {
        const int d = t >> 5, h2 = t & 31;
        float2 s = make_float2(0.f, 0.f);
        #pragma unroll
        for (int q = 0; q < 16; ++q) {
            const float2 pp = part[q][d][h2];
            s.x += pp.x; s.y += pp.y;
        }
        const float rinv = __builtin_amdgcn_rcpf(sump[0][d] + sump[1][d]);
        s.x *= rinv; s.y *= rinv;
        *(float2*)(out + (size_t)(R0 + d) * H_ + hh * 64 + 2 * h2) = s;
    }
}

extern "C" void kernel_launch(void* const* d_in, const int* in_sizes, int n_in,
                              void* d_out, int out_size, void* d_ws, size_t ws_size,
                              hipStream_t stream) {
    const float* dec = (const float*)d_in[0];
    const float* enc = (const float*)d_in[1];
    const float* Ww  = (const float*)d_in[2];
    const float* Wb  = (const float*)d_in[3];
    const float* Vw  = (const float*)d_in[4];
    float* out = (float*)d_out;

    prep_kernel<<<dim3(TENC / 32, H_ / 32, B_ + 1), dim3(32, 8), 0, stream>>>(
        enc, dec, Ww, Wb);
    score_kernel<<<dim3(B_ * (TDEC / DT) * 2), dim3(512), 0, stream>>>(Vw);
    smctx_kernel<<<dim3(B_ * (TDEC / DT) * 2), dim3(512), 0, stream>>>(enc, out);
}

// Round 5
// 72.676 us; speedup vs baseline: 1.0628x; 1.0628x over previous
//
#include <hip/hip_runtime.h>
#include <math.h>

#define B_    4
#define TDEC  512
#define TENC  1024
#define H_    128
#define DT    4

typedef float f2 __attribute__((ext_vector_type(2)));

// tanh(enc) repacked: [b][g:32][ep:512][j:4][c:2]  (thread ep reads 32B/g)
__device__ float g_tetp[(size_t)B_ * 32 * 512 * 8];            // 2 MB
// per (row-tile, g) broadcast pack: [v4(4) td_d0..d3(16) vt_d0..d3(16)] = 36 f
__device__ float g_tdvt[(size_t)B_ * 128 * 32 * 36];           // 2.25 MB
__device__ float g_scr[(size_t)B_ * TDEC * TENC];              // 8 MB raw scores

struct TDVG { float4 v4, td0, td1, td2, td3, vt0, vt1, vt2, vt3; };

union F4 { float4 v; float f[4]; };

__device__ __forceinline__ float ftanh(float x) {
    float e = __expf(2.f * x);
    return fmaf(-2.f, __builtin_amdgcn_rcpf(e + 1.f), 1.f);
}

// z<4: transpose+tanh enc -> g_tetp.   z==4: TD rows + tdvt pack.
__global__ __launch_bounds__(256) void prep_kernel(const float* __restrict__ enc,
                                                   const float* __restrict__ dec,
                                                   const float* __restrict__ Ww,
                                                   const float* __restrict__ Wb,
                                                   const float* __restrict__ Vw) {
    const int z = blockIdx.z;
    const int tx = threadIdx.x, ty = threadIdx.y;
    if (z < B_) {
        __shared__ float tile[32][33];
        const int e0 = blockIdx.x * 32, h0 = blockIdx.y * 32, b = z;
        const float* ep = enc + (size_t)b * TENC * H_;
        #pragma unroll
        for (int j = 0; j < 32; j += 8)
            tile[ty + j][tx] = ep[(size_t)(e0 + ty + j) * H_ + h0 + tx];
        __syncthreads();
        #pragma unroll
        for (int j = 0; j < 32; j += 8) {
            const int h = h0 + ty + j, e = e0 + tx;
            g_tetp[(((size_t)b * 32 + (h >> 2)) * 512 + (e >> 1)) * 8 + (h & 3) * 2 + (e & 1)]
                = ftanh(tile[tx][ty + j]);
        }
    } else {
        // 128 blocks x 16 rows: td = tanh(dec @ Ww^T + Wb); pack td & v*td
        __shared__ float ds[16][H_];
        const int t = ty * 32 + tx;
        const int blk = blockIdx.y * 32 + blockIdx.x;      // 0..127
        const int R0 = blk * 16;
        #pragma unroll
        for (int i = 0; i < 8; ++i) {
            const int f = t + 256 * i;
            ds[f >> 7][f & 127] = dec[(size_t)R0 * H_ + f];
        }
        __syncthreads();
        const int k = t & 127, dd = t >> 7;
        const float* wr = Ww + (size_t)k * H_;
        float s[8];
        #pragma unroll
        for (int j = 0; j < 8; ++j) s[j] = 0.f;
        for (int h = 0; h < H_; h += 4) {
            const float4 w4 = *(const float4*)(wr + h);
            #pragma unroll
            for (int j = 0; j < 8; ++j) {
                const float4 d4 = *(const float4*)&ds[dd + 2 * j][h];
                s[j] = fmaf(w4.x, d4.x, s[j]);
                s[j] = fmaf(w4.y, d4.y, s[j]);
                s[j] = fmaf(w4.z, d4.z, s[j]);
                s[j] = fmaf(w4.w, d4.w, s[j]);
            }
        }
        const float wb = Wb[k], vw = Vw[k];
        const int g = k >> 2, jj = k & 3;
        #pragma unroll
        for (int j = 0; j < 8; ++j) {
            const int rl = dd + 2 * j;
            const float td = ftanh(s[j] + wb);
            const size_t off = ((size_t)((R0 >> 2) + (rl >> 2)) * 32 + g) * 36;
            g_tdvt[off + 4 + (rl & 3) * 4 + jj] = td;
            g_tdvt[off + 20 + (rl & 3) * 4 + jj] = vw * td;
        }
        if (dd == 0) {
            #pragma unroll
            for (int dl = 0; dl < 4; ++dl)
                g_tdvt[((size_t)((R0 >> 2) + dl) * 32 + g) * 36 + jj] = vw;
        }
    }
}

// 4 h-terms combined per rcp, packed f32 over an e-pair.
__device__ __forceinline__ void dterms(const float4 td, const float4 vt, const float4 v4,
                                       f2 te0, f2 te1, f2 te2, f2 te3, f2& acc) {
    f2 p0 = td.x * te0 + 1.f;
    f2 p1 = td.y * te1 + 1.f;
    f2 p2 = td.z * te2 + 1.f;
    f2 p3 = td.w * te3 + 1.f;
    f2 x0 = v4.x * te0 + vt.x;
    f2 x1 = v4.y * te1 + vt.y;
    f2 x2 = v4.z * te2 + vt.z;
    f2 x3 = v4.w * te3 + vt.w;
    f2 p01 = p0 * p1, p23 = p2 * p3;
    f2 num = (x0 * p1 + x1 * p0) * p23 + (x2 * p3 + x3 * p2) * p01;
    f2 den = p01 * p23;
    f2 r;
    r.x = __builtin_amdgcn_rcpf(den.x);
    r.y = __builtin_amdgcn_rcpf(den.y);
    acc += num * r;
}

#define DALL(S, T0, T1, T2, T3)                          \
    dterms(S.td0, S.vt0, S.v4, T0, T1, T2, T3, acc0);    \
    dterms(S.td1, S.vt1, S.v4, T0, T1, T2, T3, acc1);    \
    dterms(S.td2, S.vt2, S.v4, T0, T1, T2, T3, acc2);    \
    dterms(S.td3, S.vt3, S.v4, T0, T1, T2, T3, acc3);

// grid 512 = b x 128 row-tiles; block 512 thr; thread owns e-pair (2t,2t+1).
// No LDS, no barriers; broadcasts via uniform s_loads; 2-deep prefetch.
__global__ __launch_bounds__(512) void score_kernel() {
    const int t = threadIdx.x, blk = blockIdx.x;
    const int b = blk >> 7;
    const int R0 = blk * DT;                      // global row base
    const TDVG* tp = (const TDVG*)g_tdvt + (size_t)blk * 32;
    const float* teb = g_tetp + (size_t)b * 32 * 4096 + t * 8;

    f2 acc0 = {0.f, 0.f}, acc1 = {0.f, 0.f}, acc2 = {0.f, 0.f}, acc3 = {0.f, 0.f};

    TDVG A = tp[0];
    f2 a0 = *(const f2*)(teb + 0), a1 = *(const f2*)(teb + 2);
    f2 a2 = *(const f2*)(teb + 4), a3 = *(const f2*)(teb + 6);

    for (int g = 0; g < 32; g += 2) {
        const float* tb1 = teb + (size_t)(g + 1) * 4096;
        f2 b0 = *(const f2*)(tb1 + 0), b1 = *(const f2*)(tb1 + 2);
        f2 b2 = *(const f2*)(tb1 + 4), b3 = *(const f2*)(tb1 + 6);
        TDVG Bv = tp[g + 1];

        DALL(A, a0, a1, a2, a3);

        if (g + 2 < 32) {
            const float* tb2 = teb + (size_t)(g + 2) * 4096;
            a0 = *(const f2*)(tb2 + 0); a1 = *(const f2*)(tb2 + 2);
            a2 = *(const f2*)(tb2 + 4); a3 = *(const f2*)(tb2 + 6);
            A = tp[g + 2];
        }

        DALL(Bv, b0, b1, b2, b3);
    }

    float* so = g_scr + (size_t)R0 * TENC + 2 * t;
    *(f2*)(so + 0 * TENC) = acc0;
    *(f2*)(so + 1 * TENC) = acc1;
    *(f2*)(so + 2 * TENC) = acc2;
    *(f2*)(so + 3 * TENC) = acc3;
}

// softmax + context: block = (b, row-tile of 4, h-half of 64)
__global__ __launch_bounds__(512, 8) void smctx_kernel(const float* __restrict__ enc,
                                                       float* __restrict__ out) {
    __shared__ float sc[DT][TENC];
    __shared__ float2 part[16][DT][33];
    __shared__ float maxp[2][DT], sump[2][DT];
    const int t = threadIdx.x;
    const int blk = blockIdx.x;
    const int hh = blk & 1, dt = (blk >> 1) & 127, b = blk >> 8;
    const int R0 = b * TDEC + dt * DT;

    {
        const int w = t >> 6, lane = t & 63;
        const int d = w & 3, eh = w >> 2;
        const float* sr = g_scr + (size_t)(R0 + d) * TENC + eh * 512 + lane;
        float v[8];
        float m = -3.0e38f;
        #pragma unroll
        for (int i = 0; i < 8; ++i) { v[i] = sr[i * 64]; m = fmaxf(m, v[i]); }
        #pragma unroll
        for (int off = 32; off; off >>= 1) m = fmaxf(m, __shfl_xor(m, off));
        if (lane == 0) maxp[eh][d] = m;
        __syncthreads();
        m = fmaxf(maxp[0][d], maxp[1][d]);
        float s = 0.f;
        #pragma unroll
        for (int i = 0; i < 8; ++i) {
            const float p = __expf(v[i] - m);
            sc[d][eh * 512 + lane + i * 64] = p;
            s += p;
        }
        #pragma unroll
        for (int off = 32; off; off >>= 1) s += __shfl_xor(s, off);
        if (lane == 0) sump[eh][d] = s;
    }
    __syncthreads();

    {
        const int q = t >> 5, h2 = t & 31;
        const float* eb = enc + (size_t)b * TENC * H_ + hh * 64 + 2 * h2;
        float2 acc[DT];
        #pragma unroll
        for (int d = 0; d < DT; ++d) acc[d] = make_float2(0.f, 0.f);
        for (int e = q * 64; e < q * 64 + 64; e += 4) {
            F4 p4[DT];
            #pragma unroll
            for (int d = 0; d < DT; ++d) p4[d].v = *(const float4*)&sc[d][e];
            #pragma unroll
            for (int j = 0; j < 4; ++j) {
                const float2 ev = *(const float2*)(eb + (size_t)(e + j) * H_);
                #pragma unroll
                for (int d = 0; d < DT; ++d) {
                    acc[d].x = fmaf(p4[d].f[j], ev.x, acc[d].x);
                    acc[d].y = fmaf(p4[d].f[j], ev.y, acc[d].y);
                }
            }
        }
        #pragma unroll
        for (int d = 0; d < DT; ++d) part[q][d][h2] = acc[d];
    }
    __syncthreads();

    if (t < 128) {
        const int d = t >> 5, h2 = t & 31;
        float2 s = make_float2(0.f, 0.f);
        #pragma unroll
        for (int q = 0; q < 16; ++q) {
            const float2 pp = part[q][d][h2];
            s.x += pp.x; s.y += pp.y;
        }
        const float rinv = __builtin_amdgcn_rcpf(sump[0][d] + sump[1][d]);
        s.x *= rinv; s.y *= rinv;
        *(float2*)(out + (size_t)(R0 + d) * H_ + hh * 64 + 2 * h2) = s;
    }
}

extern "C" void kernel_launch(void* const* d_in, const int* in_sizes, int n_in,
                              void* d_out, int out_size, void* d_ws, size_t ws_size,
                              hipStream_t stream) {
    const float* dec = (const float*)d_in[0];
    const float* enc = (const float*)d_in[1];
    const float* Ww  = (const float*)d_in[2];
    const float* Wb  = (const float*)d_in[3];
    const float* Vw  = (const float*)d_in[4];
    float* out = (float*)d_out;

    prep_kernel<<<dim3(TENC / 32, H_ / 32, B_ + 1), dim3(32, 8), 0, stream>>>(
        enc, dec, Ww, Wb, Vw);
    score_kernel<<<dim3(B_ * (TDEC / DT)), dim3(512), 0, stream>>>();
    smctx_kernel<<<dim3(B_ * (TDEC / DT) * 2), dim3(512), 0, stream>>>(enc, out);
}